// Round 9
// baseline (259.430 us; speedup 1.0000x reference)
//
#include <hip/hip_runtime.h>
#include <hip/hip_bf16.h>
#include <stdint.h>

typedef __attribute__((ext_vector_type(4))) float f32x4;
typedef __attribute__((ext_vector_type(8))) __bf16 bf16x8;
typedef unsigned short u16;
typedef unsigned long long u64;

__device__ __forceinline__ u16 f2bf(float f){
  unsigned u = __float_as_uint(f);
  u += 0x7fffu + ((u >> 16) & 1u);
  return (u16)(u >> 16);
}
__device__ __forceinline__ float bf2f(u16 v){
  return __uint_as_float(((unsigned)v) << 16);
}

__device__ __forceinline__ void gload16(const u16* g, u16* l){
  __builtin_amdgcn_global_load_lds(
      (__attribute__((address_space(1))) void*)g,
      (__attribute__((address_space(3))) void*)l, 16, 0, 0);
}

template<int N> __device__ __forceinline__ void waitcnt_vm(){
  if constexpr (N==0)  asm volatile("s_waitcnt vmcnt(0)" ::: "memory");
  else if constexpr (N==4)  asm volatile("s_waitcnt vmcnt(4)" ::: "memory");
  else if constexpr (N==8)  asm volatile("s_waitcnt vmcnt(8)" ::: "memory");
}

// ---- fused: fp32 rows -> bf16 + numpy-pairwise row sum-of-squares ----
__global__ __launch_bounds__(64)
void cvt_rows2(const float* __restrict__ x, const float* __restrict__ Wk,
               u16* __restrict__ xb, u16* __restrict__ wb,
               float* __restrict__ x2, float* __restrict__ w2s)
{
#pragma clang fp contract(off)
  const int bid = blockIdx.x;
  const int row = bid & 4095;
  const float* src = (bid < 4096) ? x : Wk;
  u16* dst = (bid < 4096) ? xb : wb;
  float* sq = (bid < 4096) ? x2 : w2s;
  const int l = threadIdx.x;
  const float* r = src + (size_t)row * 2048;
  const f32x4* r4 = (const f32x4*)r;
  ushort4* d4 = (ushort4*)(dst + (size_t)row * 2048);
#pragma unroll
  for (int i = 0; i < 8; i++){
    f32x4 v = r4[l + 64*i];
    ushort4 o;
    o.x = f2bf(v.x); o.y = f2bf(v.y); o.z = f2bf(v.z); o.w = f2bf(v.w);
    d4[l + 64*i] = o;
  }
  float leaf = 0.f;
  if (l < 16){
    const f32x4* p4 = (const f32x4*)(r + l*128);
    f32x4 a0 = {0.f,0.f,0.f,0.f}, a1 = {0.f,0.f,0.f,0.f};
#pragma unroll
    for (int i = 0; i < 32; i += 2){
      f32x4 v0 = p4[i], v1 = p4[i+1];
      a0 = a0 + v0*v0;
      a1 = a1 + v1*v1;
    }
    leaf = ((a0.x+a0.y)+(a0.z+a0.w))+((a1.x+a1.y)+(a1.z+a1.w));
  }
#pragma unroll
  for (int s = 1; s < 16; s <<= 1){
    float o = __shfl_down(leaf, s);
    if ((l & (2*s - 1)) == 0) leaf = leaf + o;
  }
  if (l == 0) sq[row] = leaf;
}

// ---- fused fp32 -> bf16 for w1, w2, w3 (w3 zero-padded 1024x1024) ----
__global__ __launch_bounds__(256)
void cvt_w(const float* __restrict__ w1, const float* __restrict__ w2,
           const float* __restrict__ w3,
           u16* __restrict__ w1b, u16* __restrict__ w2b, u16* __restrict__ w3b)
{
  const int N1 = 2097152;
  const int N2 = N1 + 524288;
  const int N3 = N2 + 262144;
  for (int i = blockIdx.x*256 + threadIdx.x; i < N3; i += gridDim.x*256){
    f32x4 v;
    ushort4* dp;
    if (i < N1){
      v = ((const f32x4*)w1)[i];
      dp = (ushort4*)w1b + i;
    } else if (i < N2){
      v = ((const f32x4*)w2)[i - N1];
      dp = (ushort4*)w2b + (i - N1);
    } else {
      const int j = i - N2;
      const int row = j >> 8;
      const int col4 = (j & 255)*4;
      if (row < 1000) v = *(const f32x4*)(w3 + (size_t)row*1024 + col4);
      else            v = f32x4{0.f,0.f,0.f,0.f};
      dp = (ushort4*)w3b + j;
    }
    ushort4 o;
    o.x = f2bf(v.x); o.y = f2bf(v.y); o.z = f2bf(v.z); o.w = f2bf(v.w);
    *dp = o;
  }
}

// ==== gemmW: 256x256 BK=32, anti-phase wave specialization ====
// 8 waves = 2 groups x 4. Group A (waves 0-3, SIMDs 0-3): per tile
// {read f(t); stage A(t+2); MFMA f(t)}. Group B (waves 4-7, SIMDs 0-3,
// software-pipelined one tile): {MFMA f(t-1) from regs; stage B(t+2);
// read f(t); lgkmcnt(0)}. Each SIMD = one A-wave + one B-wave, so reads
// of one group overlap MFMA of the other BY CONSTRUCTION. One barrier/tile.
// LDS: A bufs 3x16KB @0, B bufs 3x16KB @49152 (96 KB).
// Safety (rendezvous-only):
//  - stage X(t+2) -> buf[(t+2)%3] = buf[(t-1)%3]. Last reads of buf(t-1):
//    group A delivered pre-MFMA(t-1) (compiler lgkm), pre-barrier(t-1);
//    group B delivered by explicit lgkmcnt(0) pre-barrier(t-1). Stage issues
//    at tile t, i.e. after this wave crossed barrier(t-1). No overlap.
//  - vmcnt(4) per group at tile end: outstanding = own X(t+1)[4]+X(t+2)[4];
//    waits oldest 4 => X(t+1) landed pre-barrier; barrier publishes both
//    groups' produce for tile t+1.
// Epilogue: 2-pass per-wave 64x68-u16 LDS patch (136B stride, r8-proven
// conflict-free), 16B coalesced stores. Split-K piece = wg/blkpp.
__global__ __launch_bounds__(512, 2)
void gemmW(const u16* __restrict__ A, int lda,
           const u16* __restrict__ Bm, int ldb,
           u16* __restrict__ Cb, int N, int Kpp, int nbn, int blkpp)
{
  extern __shared__ char lds[];
  const int t = threadIdx.x;
  const int nwg = gridDim.x;
  const int cpx = nwg >> 3;
  const int bid = blockIdx.x;
  const int wg  = (bid & 7)*cpx + (bid >> 3);   // XCD swizzle (nwg%8==0)
  const int piece = wg / blkpp;
  const int rem = wg % blkpp;
  const int brow = (rem / nbn)*256, bcol = (rem % nbn)*256;
  const u16* Ab = A + (size_t)brow*lda + (size_t)piece*Kpp;
  const u16* Bb = Bm + (size_t)bcol*ldb + (size_t)piece*Kpp;
  u16* Cp = Cb + (size_t)piece * 4096 * N;

  const int l = t & 63, w = t >> 6;
  const bool gA = (w < 4);
  const int wr = (w & 3)*0 + ((w >> 2) ? 128 : 0) + 0;  // see below
  // wave -> output: (wm, wn) = (w>>2, w&3): group A = rows 0..127
  const int wrow = (w >> 2)*128, wcol = (w & 3)*64;
  const int fr = l & 15, fq = l >> 4;
  const int xkb = (fq ^ ((fr >> 1) & 3)) << 4;   // proven conflict-free (r3)
  const int ts = t & 255;                        // staging id within group
  const int scol = ((ts & 3) ^ ((ts >> 3) & 3))*8;  // inverse-swz source col
  const int srow = ts >> 2;                      // 0..63 per round

  auto stageA = [&](int kt, int buf){
    const u16* s0 = Ab + (size_t)srow*lda + kt*32 + scol;
    char* d = lds + buf*16384 + ts*16;
#pragma unroll
    for (int r = 0; r < 4; r++)
      gload16(s0 + (size_t)r*64*lda, (u16*)(d + r*4096));
  };
  auto stageB = [&](int kt, int buf){
    const u16* s0 = Bb + (size_t)srow*ldb + kt*32 + scol;
    char* d = lds + 49152 + buf*16384 + ts*16;
#pragma unroll
    for (int r = 0; r < 4; r++)
      gload16(s0 + (size_t)r*64*ldb, (u16*)(d + r*4096));
  };
  auto ldA = [&](int buf, int m)->bf16x8 {
    return *(const bf16x8*)(lds + buf*16384 + (wrow + m*16 + fr)*64 + xkb);
  };
  auto ldB = [&](int buf, int n)->bf16x8 {
    return *(const bf16x8*)(lds + 49152 + buf*16384 + (wcol + n*16 + fr)*64 + xkb);
  };

  f32x4 acc[8][4] = {};
  bf16x8 av[8], bv[4];
  const int nt = Kpp >> 5;

  // prologue: each group stages its tiles 0,1; own vmcnt(4) => tile0 landed
  if (gA){ stageA(0, 0); stageA(1, 1); }
  else   { stageB(0, 0); stageB(1, 1); }
  waitcnt_vm<4>();
  __builtin_amdgcn_s_barrier();

  int rb = 0, sb = 2;
  for (int kt = 0; kt < nt; kt++){
    if (gA){
#pragma unroll
      for (int m = 0; m < 8; m++) av[m] = ldA(rb, m);
#pragma unroll
      for (int n = 0; n < 4; n++) bv[n] = ldB(rb, n);
      if (kt + 2 < nt) stageA(kt + 2, sb);
      __builtin_amdgcn_s_setprio(1);
#pragma unroll
      for (int m = 0; m < 8; m++)
#pragma unroll
        for (int n = 0; n < 4; n++)
          acc[m][n] = __builtin_amdgcn_mfma_f32_16x16x32_bf16(av[m], bv[n], acc[m][n], 0, 0, 0);
      __builtin_amdgcn_s_setprio(0);
    } else {
      if (kt > 0){
        __builtin_amdgcn_s_setprio(1);
#pragma unroll
        for (int m = 0; m < 8; m++)
#pragma unroll
          for (int n = 0; n < 4; n++)
            acc[m][n] = __builtin_amdgcn_mfma_f32_16x16x32_bf16(av[m], bv[n], acc[m][n], 0, 0, 0);
        __builtin_amdgcn_s_setprio(0);
      }
      if (kt + 2 < nt) stageB(kt + 2, sb);
#pragma unroll
      for (int m = 0; m < 8; m++) av[m] = ldA(rb, m);
#pragma unroll
      for (int n = 0; n < 4; n++) bv[n] = ldB(rb, n);
      asm volatile("s_waitcnt lgkmcnt(0)" ::: "memory");  // delivered pre-barrier
    }
    if (kt + 1 < nt){
      if (kt + 2 < nt) waitcnt_vm<4>();
      else             waitcnt_vm<0>();
      __builtin_amdgcn_s_barrier();
    }
    rb = (rb + 1 == 3) ? 0 : rb + 1;
    sb = (sb + 1 == 3) ? 0 : sb + 1;
  }
  if (!gA){
    __builtin_amdgcn_s_setprio(1);
#pragma unroll
    for (int m = 0; m < 8; m++)
#pragma unroll
      for (int n = 0; n < 4; n++)
        acc[m][n] = __builtin_amdgcn_mfma_f32_16x16x32_bf16(av[m], bv[n], acc[m][n], 0, 0, 0);
    __builtin_amdgcn_s_setprio(0);
  }

  // ---- epilogue: 2-pass 64x68-u16 patch per wave (conflict-free) ----
  __builtin_amdgcn_s_barrier();       // K-loop LDS reads all delivered
  u16* ep = (u16*)(lds + w*8704);
  const int erow = l >> 3, ecb = (l & 7)*16;
#pragma unroll
  for (int h = 0; h < 2; h++){
#pragma unroll
    for (int m = 0; m < 4; m++)
#pragma unroll
      for (int n = 0; n < 4; n++)
#pragma unroll
        for (int r = 0; r < 4; r++)
          ep[(m*16 + fq*4 + r)*68 + n*16 + fr] = f2bf(acc[h*4 + m][n][r]);
    asm volatile("s_waitcnt lgkmcnt(0)" ::: "memory");
#pragma unroll
    for (int it = 0; it < 8; it++){
      const int row = it*8 + erow;
      f32x4 v = *(const f32x4*)((const char*)ep + row*136 + ecb);
      char* gp = (char*)Cp + (((size_t)(brow + wrow + h*64 + row))*N + (bcol + wcol))*2 + ecb;
      *(f32x4*)gp = v;
    }
    asm volatile("s_waitcnt lgkmcnt(0)" ::: "memory");  // reads done pre-rewrite
  }
}

// ---- combine split-K partials + bias + relu -> bf16 ----
__global__ __launch_bounds__(256)
void combine_relu(const u16* __restrict__ p0, const u16* __restrict__ p1,
                  const float* __restrict__ bias, u16* __restrict__ out)
{
  const int n4 = 4096*2048/4;
  for (int i = blockIdx.x*256 + threadIdx.x; i < n4; i += gridDim.x*256){
    ushort4 a = ((const ushort4*)p0)[i];
    ushort4 b = ((const ushort4*)p1)[i];
    const int col = (i*4) & 2047;
    f32x4 bi = *(const f32x4*)(bias + col);
    ushort4 o;
    o.x = f2bf(fmaxf(bf2f(a.x) + bf2f(b.x) + bi.x, 0.f));
    o.y = f2bf(fmaxf(bf2f(a.y) + bf2f(b.y) + bi.y, 0.f));
    o.z = f2bf(fmaxf(bf2f(a.z) + bf2f(b.z) + bi.z, 0.f));
    o.w = f2bf(fmaxf(bf2f(a.w) + bf2f(b.w) + bi.w, 0.f));
    ((ushort4*)out)[i] = o;
  }
}

// ---- small-GEMM pipeline (G3/G4), unchanged from r8 ----
template<int BM, int BN, int WM, int WN, int EPI, int MINW>
__global__ __launch_bounds__(WM*WN*64, MINW)
void gemm_p(const u16* __restrict__ A, const u16* __restrict__ Bm,
            float* __restrict__ Cf, u16* __restrict__ Cb,
            const float* __restrict__ bias,
            int M, int N, int K, int ncols, int nbn)
{
  constexpr int T  = WM*WN*64;
  constexpr int FM = BM/(WM*16);
  constexpr int FN = BN/(WN*16);
  constexpr int ABYTES = BM*64;
  constexpr int BUFB   = (BM+BN)*64;
  constexpr int RA = ABYTES/(T*16);
  constexpr int RB = (BN*64)/(T*16);
  extern __shared__ char lds[];

  const int t = threadIdx.x;
  const int nwg = gridDim.x;
  const int cpx = nwg >> 3;
  const int bid = blockIdx.x;
  const int wg  = (bid & 7)*cpx + (bid >> 3);
  const int bm = wg / nbn, bn = wg % nbn;
  const int brow = bm*BM, bcol = bn*BN;

  const int l = t & 63, w = t >> 6;
  const int wm = w / WN, wn = w % WN;
  const int wr = wm*(FM*16), wc = wn*(FN*16);
  const int fr = l & 15, fq = l >> 4, fk = fq*8;
  const int xk = fk ^ (((fr >> 1) & 3) << 3);

  const int srow = t >> 2;
  const int scol = ((t & 3)*8) ^ (((t >> 3) & 3) << 3);

  const u16* agp[RA]; const u16* bgp[RB];
#pragma unroll
  for (int r = 0; r < RA; r++)
    agp[r] = A + (size_t)(brow + r*(T>>2) + srow)*K + scol;
#pragma unroll
  for (int r = 0; r < RB; r++)
    bgp[r] = Bm + (size_t)(bcol + r*(T>>2) + srow)*K + scol;

  f32x4 acc[FM][FN] = {};
  const int nt = K >> 5;

  auto stageA = [&](int kt, int buf){
    char* dst = lds + buf*BUFB + t*16;
#pragma unroll
    for (int r = 0; r < RA; r++)
      gload16(agp[r] + (kt << 5), (u16*)(dst + r*T*16));
  };
  auto stageB = [&](int kt, int buf){
    char* dst = lds + buf*BUFB + ABYTES + t*16;
#pragma unroll
    for (int r = 0; r < RB; r++)
      gload16(bgp[r] + (kt << 5), (u16*)(dst + r*T*16));
  };

  stageA(0, 0); stageB(0, 0);
  stageA(1, 1); stageB(1, 1);
  stageA(2, 2); stageB(2, 2);
  waitcnt_vm<8>();
  __builtin_amdgcn_s_barrier();

  for (int kt = 0; kt < nt; kt++){
    const int buf = kt & 3;
    const u16* As = (const u16*)(lds + buf*BUFB);
    const u16* Bs = (const u16*)(lds + buf*BUFB + ABYTES);
    const bool pre = (kt + 3 < nt);
    const int nbuf = (kt + 3) & 3;

    bf16x8 av[FM], bv[FN];
#pragma unroll
    for (int m = 0; m < FM; m++)
      av[m] = *(const bf16x8*)(As + (wr + m*16 + fr)*32 + xk);
#pragma unroll
    for (int n = 0; n < FN; n++)
      bv[n] = *(const bf16x8*)(Bs + (wc + n*16 + fr)*32 + xk);
    if (pre){ stageA(kt + 3, nbuf); stageB(kt + 3, nbuf); }
    __builtin_amdgcn_s_setprio(1);
#pragma unroll
    for (int m = 0; m < FM; m++)
#pragma unroll
      for (int n = 0; n < FN; n++)
        acc[m][n] = __builtin_amdgcn_mfma_f32_16x16x32_bf16(av[m], bv[n], acc[m][n], 0, 0, 0);
    __builtin_amdgcn_s_setprio(0);

    if (kt + 1 < nt){
      if (kt + 3 < nt)      waitcnt_vm<8>();
      else if (kt + 2 < nt) waitcnt_vm<4>();
      else                  waitcnt_vm<0>();
      __builtin_amdgcn_s_barrier();
    }
  }

  __builtin_amdgcn_s_barrier();
  if (EPI == 1){
    u16* ep = (u16*)(lds + w*8192);
#pragma unroll
    for (int n = 0; n < FN; n++){
      const float bvv = bias[bcol + wc + n*16 + fr];
#pragma unroll
      for (int m = 0; m < FM; m++)
#pragma unroll
        for (int r = 0; r < 4; r++)
          ep[(m*16 + fq*4 + r)*64 + n*16 + fr] = f2bf(fmaxf(acc[m][n][r] + bvv, 0.f));
    }
    asm volatile("s_waitcnt lgkmcnt(0)" ::: "memory");
    const int erow = l >> 3, ecb = (l & 7)*16;
#pragma unroll
    for (int it = 0; it < 8; it++){
      const int row = it*8 + erow;
      f32x4 v = *(const f32x4*)((const char*)ep + row*128 + ecb);
      char* gp = (char*)Cb + (((size_t)(brow + wr + row))*N + (bcol + wc))*2 + ecb;
      *(f32x4*)gp = v;
    }
  } else {
    float* ep = (float*)(lds + w*16384);
#pragma unroll
    for (int n = 0; n < FN; n++){
      const int gcol = bcol + wc + n*16 + fr;
      const float bvv = (gcol < ncols) ? bias[gcol] : 0.f;
#pragma unroll
      for (int m = 0; m < FM; m++)
#pragma unroll
        for (int r = 0; r < 4; r++)
          ep[(m*16 + fq*4 + r)*64 + n*16 + fr] = acc[m][n][r] + bvv;
    }
    asm volatile("s_waitcnt lgkmcnt(0)" ::: "memory");
    const int erow = l >> 4, ecb = (l & 15)*16;
    const int gcol0 = bcol + wc + (l & 15)*4;
#pragma unroll
    for (int it = 0; it < 16; it++){
      const int row = it*4 + erow;
      f32x4 v = *(const f32x4*)((const char*)ep + row*256 + ecb);
      if (gcol0 < ncols)
        *(f32x4*)(Cf + (size_t)(brow + wr + row)*ncols + gcol0) = v;
    }
  }
}

// ---- per-row: distances, argmin (exact fp64-refined candidates), softmax ----
__global__ __launch_bounds__(256)
void row_softmax(const u16* __restrict__ Sb, const float* __restrict__ x2,
                 const float* __restrict__ w2sq,
                 const float* __restrict__ x, const float* __restrict__ W,
                 u16* __restrict__ soft, float* __restrict__ winners)
{
  const int b = blockIdx.x, t = threadIdx.x;
  const float x2b = x2[b];
  const ushort4* S4 = (const ushort4*)(Sb + (size_t)b*4096);
  const f32x4* W24 = (const f32x4*)w2sq;
  float dv[16];
  float bd = 3.0e38f; int bc = 0;
#pragma unroll
  for (int i = 0; i < 4; i++){
    ushort4 s = S4[t + 256*i];
    f32x4 wv = W24[t + 256*i];
    float sf[4] = {bf2f(s.x), bf2f(s.y), bf2f(s.z), bf2f(s.w)};
#pragma unroll
    for (int j = 0; j < 4; j++){
      float u = x2b + wv[j];
      float d2 = u - 2.0f*sf[j];
      float d = __fsqrt_rn(fmaxf(d2, 1e-12f));
      dv[i*4 + j] = d;
      if (d < bd){ bd = d; bc = (t + 256*i)*4 + j; }
    }
  }
  u64 key = ((u64)__float_as_uint(bd) << 32) | (unsigned)bc;
#pragma unroll
  for (int s = 1; s < 64; s <<= 1){
    u64 o = __shfl_xor(key, s);
    if (o < key) key = o;
  }
  __shared__ u64 wk[4];
  __shared__ double csum[4];
  __shared__ float fred[4];
  __shared__ int ccnt;
  __shared__ int cand[32];
  if ((t & 63) == 0) wk[t >> 6] = key;
  if (t == 0) ccnt = 0;
  __syncthreads();
  u64 k0 = wk[0];
  if (wk[1] < k0) k0 = wk[1];
  if (wk[2] < k0) k0 = wk[2];
  if (wk[3] < k0) k0 = wk[3];
  const float dmin = __uint_as_float((unsigned)(k0 >> 32));

  const float thr = dmin + 0.01f;
#pragma unroll
  for (int i = 0; i < 4; i++)
#pragma unroll
    for (int j = 0; j < 4; j++)
      if (dv[i*4 + j] <= thr){
        int p = atomicAdd(&ccnt, 1);
        if (p < 32) cand[p] = (t + 256*i)*4 + j;
      }
  __syncthreads();
  const int nc = min(ccnt, 32);

  float bestd = 3.0e38f; int besti = 0x7fffffff;
  const f32x4* xp = (const f32x4*)(x + (size_t)b*2048) + t*2;
  f32x4 xv0 = xp[0], xv1 = xp[1];
  for (int c = 0; c < nc; c++){
    const int h = cand[c];
    const f32x4* wp = (const f32x4*)(W + (size_t)h*2048) + t*2;
    f32x4 wv0 = wp[0], wv1 = wp[1];
    double a = 0.0;
#pragma unroll
    for (int j = 0; j < 4; j++) a += (double)xv0[j]*(double)wv0[j];
#pragma unroll
    for (int j = 0; j < 4; j++) a += (double)xv1[j]*(double)wv1[j];
#pragma unroll
    for (int s = 1; s < 64; s <<= 1) a += __shfl_xor(a, s);
    if ((t & 63) == 0) csum[t >> 6] = a;
    __syncthreads();
    if (t == 0){
      double tt = (csum[0] + csum[1]) + (csum[2] + csum[3]);
      float t32 = (float)tt;
      float u = x2b + w2sq[h];
      float d2 = u - 2.0f*t32;
      float d = __fsqrt_rn(fmaxf(d2, 1e-12f));
      if (d < bestd || (d == bestd && h < besti)){ bestd = d; besti = h; }
    }
    __syncthreads();
  }
  if (t == 0) winners[b] = (float)besti;

  float es = 0.f;
#pragma unroll
  for (int i = 0; i < 16; i++) es += __expf(-2.0f*(dv[i] - dmin));
#pragma unroll
  for (int s = 1; s < 64; s <<= 1) es += __shfl_xor(es, s);
  if ((t & 63) == 0) fred[t >> 6] = es;
  __syncthreads();
  const float tot = (fred[0] + fred[1]) + (fred[2] + fred[3]);
  const float inv = 1.0f / tot;
  ushort4* o4 = (ushort4*)(soft + (size_t)b*4096);
#pragma unroll
  for (int i = 0; i < 4; i++){
    ushort4 o;
    o.x = f2bf(__expf(-2.0f*(dv[i*4+0] - dmin))*inv);
    o.y = f2bf(__expf(-2.0f*(dv[i*4+1] - dmin))*inv);
    o.z = f2bf(__expf(-2.0f*(dv[i*4+2] - dmin))*inv);
    o.w = f2bf(__expf(-2.0f*(dv[i*4+3] - dmin))*inv);
    o4[t + 256*i] = o;
  }
}

extern "C" void kernel_launch(void* const* d_in, const int* in_sizes, int n_in,
                              void* d_out, int out_size, void* d_ws, size_t ws_size,
                              hipStream_t stream)
{
  const float* x  = (const float*)d_in[0];
  const float* Wk = (const float*)d_in[1];
  const float* w1 = (const float*)d_in[2];
  const float* b1 = (const float*)d_in[3];
  const float* w2 = (const float*)d_in[4];
  const float* b2 = (const float*)d_in[5];
  const float* w3 = (const float*)d_in[6];
  const float* b3 = (const float*)d_in[7];
  float* out = (float*)d_out;
  float* winners = out + (size_t)4096*1000;

  char* ws = (char*)d_ws;
  const size_t MB = 1u << 20;
  u16* Sb    = (u16*)(ws);                // 32MB bf16 S [dead after row_softmax]
  u16* soft  = (u16*)(ws + 32*MB);        // 32MB
  u16* w1b   = (u16*)(ws + 64*MB);        // 16MB
  u16* w2b   = (u16*)(ws + 80*MB);        // 4MB
  u16* w3b   = (u16*)(ws + 84*MB);        // 2MB (padded 1024x1024)
  float* x2  = (float*)(ws + 86*MB);      // 16KB
  float* w2s = x2 + 4096;                 // 16KB
  u16* xb    = (u16*)(ws + 88*MB);        // 16MB [dead after gemm1]
  u16* wb    = (u16*)(ws + 104*MB);       // 16MB [dead after gemm1]
  u16* P0    = (u16*)(ws + 88*MB);        // 16MB splitK partial, overlays xb
  u16* P1    = (u16*)(ws + 104*MB);       // 16MB partial, overlays wb
  u16* h1    = (u16*)(ws);                // 16MB overlays Sb
  u16* h2    = (u16*)(ws + 16*MB);        // 8MB  overlays Sb

  cvt_rows2<<<8192, 64, 0, stream>>>(x, Wk, xb, wb, x2, w2s);
  cvt_w<<<2048, 256, 0, stream>>>(w1, w2, w3, w1b, w2b, w3b);

  hipFuncSetAttribute((const void*)gemmW,
                      hipFuncAttributeMaxDynamicSharedMemorySize, 98304);

  // S = x @ W^T -> bf16  (256^2, anti-phase waves, 96KB LDS)
  gemmW<<<256, 512, 98304, stream>>>(xb, 2048, wb, 2048, Sb,
                                     4096, 2048, 16, 256);

  // distances -> winners (exact refine) + soft (bf16)
  row_softmax<<<4096, 256, 0, stream>>>(Sb, x2, w2s, x, Wk, soft, winners);

  // h1 = relu(soft @ w1^T + b1): split-K x2 + combine
  gemmW<<<256, 512, 98304, stream>>>(soft, 4096, w1b, 4096, P0,
                                     2048, 2048, 8, 128);
  combine_relu<<<2048, 256, 0, stream>>>(P0, P1, b1, h1);

  // h2 = relu(h1 @ w2^T + b2)   (128^2 tile, 4 waves, 64KB LDS)
  hipFuncSetAttribute((const void*)gemm_p<128,128,2,2,1,3>,
                      hipFuncAttributeMaxDynamicSharedMemorySize, 4*256*64);
  gemm_p<128,128,2,2,1,3><<<256, 256, 4*256*64, stream>>>(
      h1, w2b, nullptr, h2, b2, 4096, 1024, 2048, 0, 8);

  // out = h2 @ w3^T + b3  (fp32, 1000 valid cols)
  hipFuncSetAttribute((const void*)gemm_p<128,128,2,2,2,3>,
                      hipFuncAttributeMaxDynamicSharedMemorySize, 4*256*64);
  gemm_p<128,128,2,2,2,3><<<256, 256, 4*256*64, stream>>>(
      h2, w3b, out, nullptr, b3, 4096, 1024, 1024, 1000, 8);
}